// Round 1
// baseline (1509.271 us; speedup 1.0000x reference)
//
#include <hip/hip_runtime.h>

#define BN 4096      // N = H*W
#define NCH 256      // C
#define DQ 32        // D = C/8

// ---------------------------------------------------------------------------
// Projection: q = Wq x + bq (32xN), k = Wk x + bk (32xN), vT = (Wv x + bv)^T
// grid (N/256, 10, B); block row-groups: ry=0 -> q, ry=1 -> k, ry>=2 -> 32 V rows
// ---------------------------------------------------------------------------
__global__ __launch_bounds__(256) void proj_kernel(
    const float* __restrict__ x,
    const float* __restrict__ Wq, const float* __restrict__ bq,
    const float* __restrict__ Wk, const float* __restrict__ bk,
    const float* __restrict__ Wv, const float* __restrict__ bv,
    float* __restrict__ qo, float* __restrict__ ko, float* __restrict__ vT)
{
    const int t  = threadIdx.x;
    const int n0 = blockIdx.x * 256;
    const int ry = blockIdx.y;
    const int b  = blockIdx.z;

    __shared__ __align__(16) float xs[32 * 256];   // [cin][n]
    __shared__ float Wt[32 * 33];                  // [cin][row], padded

    const float* Wsrc; const float* bsrc; int row0; bool isV = false;
    if (ry == 0)      { Wsrc = Wq; bsrc = bq; row0 = 0; }
    else if (ry == 1) { Wsrc = Wk; bsrc = bk; row0 = 0; }
    else              { Wsrc = Wv; bsrc = bv; row0 = (ry - 2) * 32; isV = true; }

    const int tr  = (t >> 6) * 8;     // q/k: row group (wave-uniform)
    const int tnq = (t & 63) * 4;     // q/k: n group
    const int tcv = (t & 7) * 4;      // v: c group
    const int tnv = (t >> 3) * 8;     // v: n group

    float acc[8][4];
    if (!isV) {
#pragma unroll
        for (int r = 0; r < 8; ++r) {
            float bb = bsrc[tr + r];
#pragma unroll
            for (int j = 0; j < 4; ++j) acc[r][j] = bb;
        }
    } else {
#pragma unroll
        for (int e = 0; e < 4; ++e) {
            float bb = bsrc[row0 + tcv + e];
#pragma unroll
            for (int i = 0; i < 8; ++i) acc[i][e] = bb;
        }
    }

    for (int cc = 0; cc < 256; cc += 32) {
        // stage W tile (transpose into [cin][row], pad 33)
        {
            int r  = t >> 3;
            int c4 = (t & 7) * 4;
            float4 wv = *(const float4*)&Wsrc[(row0 + r) * 256 + cc + c4];
            Wt[(c4 + 0) * 33 + r] = wv.x;
            Wt[(c4 + 1) * 33 + r] = wv.y;
            Wt[(c4 + 2) * 33 + r] = wv.z;
            Wt[(c4 + 3) * 33 + r] = wv.w;
        }
        // stage x tile [cin][n]
#pragma unroll
        for (int i = 0; i < 8; ++i) {
            int idx = t + i * 256;
            int ci  = idx >> 6;
            int n4  = (idx & 63) * 4;
            *(float4*)&xs[ci * 256 + n4] =
                *(const float4*)&x[(b * NCH + cc + ci) * BN + n0 + n4];
        }
        __syncthreads();

        if (!isV) {
#pragma unroll 8
            for (int ci = 0; ci < 32; ++ci) {
                float4 xv = *(const float4*)&xs[ci * 256 + tnq];
#pragma unroll
                for (int r = 0; r < 8; ++r) {
                    float w = Wt[ci * 33 + tr + r];   // wave-uniform broadcast
                    acc[r][0] += w * xv.x;
                    acc[r][1] += w * xv.y;
                    acc[r][2] += w * xv.z;
                    acc[r][3] += w * xv.w;
                }
            }
        } else {
#pragma unroll 8
            for (int ci = 0; ci < 32; ++ci) {
                float4 xa = *(const float4*)&xs[ci * 256 + tnv];
                float4 xb = *(const float4*)&xs[ci * 256 + tnv + 4];
#pragma unroll
                for (int e = 0; e < 4; ++e) {
                    float w = Wt[ci * 33 + tcv + e];
                    acc[0][e] += w * xa.x;
                    acc[1][e] += w * xa.y;
                    acc[2][e] += w * xa.z;
                    acc[3][e] += w * xa.w;
                    acc[4][e] += w * xb.x;
                    acc[5][e] += w * xb.y;
                    acc[6][e] += w * xb.z;
                    acc[7][e] += w * xb.w;
                }
            }
        }
        __syncthreads();
    }

    if (!isV) {
        float* outp = (ry == 0) ? qo : ko;
#pragma unroll
        for (int r = 0; r < 8; ++r) {
            float4 o = make_float4(acc[r][0], acc[r][1], acc[r][2], acc[r][3]);
            *(float4*)&outp[(b * DQ + tr + r) * BN + n0 + tnq] = o;
        }
    } else {
#pragma unroll
        for (int i = 0; i < 8; ++i) {
            float4 o = make_float4(acc[i][0], acc[i][1], acc[i][2], acc[i][3]);
            *(float4*)&vT[(size_t)(b * BN + n0 + tnv + i) * NCH + row0 + tcv] = o;
        }
    }
}

// ---------------------------------------------------------------------------
// Flash attention, single pass. grid (N/64, B), block 256.
// Per block: 64-query tile, full C=256 output channels in registers (4n x 16c
// per thread). Iterate 32-key chunks: S = q^T k, online softmax, O += V P^T.
// Epilogue: O/l + x residual, coalesced float4 stores.
// ---------------------------------------------------------------------------
__global__ __launch_bounds__(256) void flash_kernel(
    const float* __restrict__ q, const float* __restrict__ k,
    const float* __restrict__ vT, const float* __restrict__ x,
    float* __restrict__ out)
{
    const int t  = threadIdx.x;
    const int n0 = blockIdx.x * 64;
    const int b  = blockIdx.y;

    __shared__ __align__(16) float qs[32 * 64];    // [d][n]
    __shared__ __align__(16) float ks[32 * 32];    // [d][m]
    __shared__ __align__(16) float vs[32 * 256];   // [m][c]
    __shared__ float Ps[64 * 33];                  // [n][m], padded
    __shared__ float alph[64];
    __shared__ float m_i[64];
    __shared__ float l_i[64];

#pragma unroll
    for (int i = 0; i < 2; ++i) {
        int idx = t + i * 256;
        int d = idx >> 4, n4 = (idx & 15) * 4;
        *(float4*)&qs[d * 64 + n4] = *(const float4*)&q[(b * DQ + d) * BN + n0 + n4];
    }
    if (t < 64) { m_i[t] = -1e30f; l_i[t] = 0.0f; }

    float acc[4][16];
#pragma unroll
    for (int j = 0; j < 4; ++j)
#pragma unroll
        for (int c = 0; c < 16; ++c) acc[j][c] = 0.0f;

    const int u  = t & 15;
    const int w  = t >> 4;
    const int tn = u * 4;     // query rows (S, PV, epilogue)
    const int tm = w * 2;     // key pair (S phase)
    const int tc = w * 16;    // channel group (PV, epilogue)

    __syncthreads();

    for (int mc = 0; mc < BN; mc += 32) {
        // ---- stage K chunk [d][m] and V chunk [m][c] ----
        {
            int d = t >> 3, m4 = (t & 7) * 4;
            *(float4*)&ks[d * 32 + m4] = *(const float4*)&k[(b * DQ + d) * BN + mc + m4];
        }
#pragma unroll
        for (int i = 0; i < 8; ++i) {
            int idx = t + i * 256;
            int m = idx >> 6, c4 = (idx & 63) * 4;
            *(float4*)&vs[m * 256 + c4] =
                *(const float4*)&vT[(size_t)(b * BN + mc + m) * NCH + c4];
        }
        __syncthreads();

        // ---- S = q^T k : 4n x 2m per thread ----
        float s00 = 0, s01 = 0, s10 = 0, s11 = 0, s20 = 0, s21 = 0, s30 = 0, s31 = 0;
#pragma unroll 8
        for (int d = 0; d < 32; ++d) {
            float4 qv = *(const float4*)&qs[d * 64 + tn];
            float k0 = ks[d * 32 + tm];
            float k1 = ks[d * 32 + tm + 1];
            s00 += qv.x * k0; s01 += qv.x * k1;
            s10 += qv.y * k0; s11 += qv.y * k1;
            s20 += qv.z * k0; s21 += qv.z * k1;
            s30 += qv.w * k0; s31 += qv.w * k1;
        }
        Ps[(tn + 0) * 33 + tm] = s00; Ps[(tn + 0) * 33 + tm + 1] = s01;
        Ps[(tn + 1) * 33 + tm] = s10; Ps[(tn + 1) * 33 + tm + 1] = s11;
        Ps[(tn + 2) * 33 + tm] = s20; Ps[(tn + 2) * 33 + tm + 1] = s21;
        Ps[(tn + 3) * 33 + tm] = s30; Ps[(tn + 3) * 33 + tm + 1] = s31;
        __syncthreads();

        // ---- online softmax stats (one thread per query row) ----
        if (t < 64) {
            float mo = m_i[t];
            float cmax = -1e30f;
#pragma unroll 8
            for (int m = 0; m < 32; ++m) cmax = fmaxf(cmax, Ps[t * 33 + m]);
            float mn = fmaxf(mo, cmax);
            float al = __expf(mo - mn);
            float cs = 0.0f;
#pragma unroll 8
            for (int m = 0; m < 32; ++m) {
                float p = __expf(Ps[t * 33 + m] - mn);
                Ps[t * 33 + m] = p;
                cs += p;
            }
            l_i[t] = l_i[t] * al + cs;
            m_i[t] = mn;
            alph[t] = al;
        }
        __syncthreads();

        // ---- O = O*alpha + V @ P^T ----
        float a0 = alph[tn], a1 = alph[tn + 1], a2 = alph[tn + 2], a3 = alph[tn + 3];
#pragma unroll
        for (int c = 0; c < 16; ++c) {
            acc[0][c] *= a0; acc[1][c] *= a1; acc[2][c] *= a2; acc[3][c] *= a3;
        }
#pragma unroll 4
        for (int kk = 0; kk < 32; ++kk) {
            float p0 = Ps[(tn + 0) * 33 + kk];
            float p1 = Ps[(tn + 1) * 33 + kk];
            float p2 = Ps[(tn + 2) * 33 + kk];
            float p3 = Ps[(tn + 3) * 33 + kk];
            const float4* vrow = (const float4*)&vs[kk * 256 + tc];
#pragma unroll
            for (int c4 = 0; c4 < 4; ++c4) {
                float4 vv = vrow[c4];
                int c = c4 * 4;
                acc[0][c + 0] += p0 * vv.x; acc[0][c + 1] += p0 * vv.y;
                acc[0][c + 2] += p0 * vv.z; acc[0][c + 3] += p0 * vv.w;
                acc[1][c + 0] += p1 * vv.x; acc[1][c + 1] += p1 * vv.y;
                acc[1][c + 2] += p1 * vv.z; acc[1][c + 3] += p1 * vv.w;
                acc[2][c + 0] += p2 * vv.x; acc[2][c + 1] += p2 * vv.y;
                acc[2][c + 2] += p2 * vv.z; acc[2][c + 3] += p2 * vv.w;
                acc[3][c + 0] += p3 * vv.x; acc[3][c + 1] += p3 * vv.y;
                acc[3][c + 2] += p3 * vv.z; acc[3][c + 3] += p3 * vv.w;
            }
        }
        __syncthreads();
    }

    // ---- epilogue: /l, +x residual, coalesced stores ----
    float linv0 = 1.0f / l_i[tn + 0];
    float linv1 = 1.0f / l_i[tn + 1];
    float linv2 = 1.0f / l_i[tn + 2];
    float linv3 = 1.0f / l_i[tn + 3];
#pragma unroll
    for (int c16 = 0; c16 < 16; ++c16) {
        int c = tc + c16;
        const float4 xv = *(const float4*)&x[(b * NCH + c) * BN + n0 + tn];
        float4 o;
        o.x = acc[0][c16] * linv0 + xv.x;
        o.y = acc[1][c16] * linv1 + xv.y;
        o.z = acc[2][c16] * linv2 + xv.z;
        o.w = acc[3][c16] * linv3 + xv.w;
        *(float4*)&out[(b * NCH + c) * BN + n0 + tn] = o;
    }
}

extern "C" void kernel_launch(void* const* d_in, const int* in_sizes, int n_in,
                              void* d_out, int out_size, void* d_ws, size_t ws_size,
                              hipStream_t stream)
{
    const float* x  = (const float*)d_in[0];
    const float* Wq = (const float*)d_in[1];
    const float* bq = (const float*)d_in[2];
    const float* Wk = (const float*)d_in[3];
    const float* bk = (const float*)d_in[4];
    const float* Wv = (const float*)d_in[5];
    const float* bv = (const float*)d_in[6];
    float* out = (float*)d_out;

    float* ws = (float*)d_ws;
    float* qb = ws;                          // 8*32*4096 floats  (4 MB)
    float* kb = qb + 8 * DQ * BN;            // 8*32*4096 floats  (4 MB)
    float* vT = kb + 8 * DQ * BN;            // 8*4096*256 floats (32 MB)

    proj_kernel<<<dim3(16, 10, 8), 256, 0, stream>>>(x, Wq, bq, Wk, bk, Wv, bv, qb, kb, vT);
    flash_kernel<<<dim3(BN / 64, 8), 256, 0, stream>>>(qb, kb, vT, x, out);
}

// Round 2
// 485.591 us; speedup vs baseline: 3.1081x; 3.1081x over previous
//
#include <hip/hip_runtime.h>

#define BN 4096      // N = H*W
#define NCH 256      // C
#define DQ 32        // D = C/8

typedef _Float16 half8  __attribute__((ext_vector_type(8)));
typedef _Float16 half4  __attribute__((ext_vector_type(4)));
typedef float   floatx4  __attribute__((ext_vector_type(4)));
typedef float   floatx16 __attribute__((ext_vector_type(16)));

#define ROWV 72   // vs row stride (f16): 144 B, 16-aligned, bank-spread
#define ROWP 80   // Ps row stride (f16): 160 B, 16-aligned, bank-spread

// ---------------------------------------------------------------------------
// Projection -> f16: qb[b][d][n], kT[b][n][d] (transposed), vb[b][c][n]
// grid (16, 10, B): ry=0 -> q, ry=1 -> k (col micro-tile), ry>=2 -> 32 V rows
// ---------------------------------------------------------------------------
__global__ __launch_bounds__(256) void proj_kernel(
    const float* __restrict__ x,
    const float* __restrict__ Wq, const float* __restrict__ bq,
    const float* __restrict__ Wk, const float* __restrict__ bk,
    const float* __restrict__ Wv, const float* __restrict__ bv,
    _Float16* __restrict__ qb, _Float16* __restrict__ kT, _Float16* __restrict__ vb)
{
    const int t  = threadIdx.x;
    const int n0 = blockIdx.x * 256;
    const int ry = blockIdx.y;
    const int b  = blockIdx.z;

    __shared__ __align__(16) float xs[32 * 256];   // [cin][n]
    __shared__ float Wt[32 * 33];                  // [cin][row], padded

    const float* Wsrc; const float* bsrc; int row0; const bool isK = (ry == 1);
    if (ry == 0)      { Wsrc = Wq; bsrc = bq; row0 = 0; }
    else if (ry == 1) { Wsrc = Wk; bsrc = bk; row0 = 0; }
    else              { Wsrc = Wv; bsrc = bv; row0 = (ry - 2) * 32; }

    const int tr  = (t >> 6) * 8;     // row-major micro-tile: 8 rows x 4 n
    const int tnq = (t & 63) * 4;
    const int tdk = (t & 7) * 4;      // col-major micro-tile (k): 4 rows x 8 n
    const int tnk = (t >> 3) * 8;

    float acc[8][4];
    if (!isK) {
#pragma unroll
        for (int r = 0; r < 8; ++r) {
            float bb = bsrc[row0 + tr + r];
#pragma unroll
            for (int j = 0; j < 4; ++j) acc[r][j] = bb;
        }
    } else {
#pragma unroll
        for (int e = 0; e < 4; ++e) {
            float bb = bsrc[tdk + e];
#pragma unroll
            for (int i = 0; i < 8; ++i) acc[i][e] = bb;
        }
    }

    for (int cc = 0; cc < 256; cc += 32) {
        {
            int r  = t >> 3;
            int c4 = (t & 7) * 4;
            float4 wv = *(const float4*)&Wsrc[(row0 + r) * 256 + cc + c4];
            Wt[(c4 + 0) * 33 + r] = wv.x;
            Wt[(c4 + 1) * 33 + r] = wv.y;
            Wt[(c4 + 2) * 33 + r] = wv.z;
            Wt[(c4 + 3) * 33 + r] = wv.w;
        }
#pragma unroll
        for (int i = 0; i < 8; ++i) {
            int idx = t + i * 256;
            int ci  = idx >> 6;
            int n4  = (idx & 63) * 4;
            *(float4*)&xs[ci * 256 + n4] =
                *(const float4*)&x[(b * NCH + cc + ci) * BN + n0 + n4];
        }
        __syncthreads();

        if (!isK) {
#pragma unroll 8
            for (int ci = 0; ci < 32; ++ci) {
                float4 xv = *(const float4*)&xs[ci * 256 + tnq];
#pragma unroll
                for (int r = 0; r < 8; ++r) {
                    float w = Wt[ci * 33 + tr + r];
                    acc[r][0] += w * xv.x;
                    acc[r][1] += w * xv.y;
                    acc[r][2] += w * xv.z;
                    acc[r][3] += w * xv.w;
                }
            }
        } else {
#pragma unroll 8
            for (int ci = 0; ci < 32; ++ci) {
                float4 xa = *(const float4*)&xs[ci * 256 + tnk];
                float4 xb = *(const float4*)&xs[ci * 256 + tnk + 4];
#pragma unroll
                for (int e = 0; e < 4; ++e) {
                    float w = Wt[ci * 33 + tdk + e];
                    acc[0][e] += w * xa.x;
                    acc[1][e] += w * xa.y;
                    acc[2][e] += w * xa.z;
                    acc[3][e] += w * xa.w;
                    acc[4][e] += w * xb.x;
                    acc[5][e] += w * xb.y;
                    acc[6][e] += w * xb.z;
                    acc[7][e] += w * xb.w;
                }
            }
        }
        __syncthreads();
    }

    if (!isK) {
        _Float16* outp = (ry == 0) ? (qb + (size_t)b * DQ * BN)
                                   : (vb + (size_t)b * NCH * BN);
#pragma unroll
        for (int r = 0; r < 8; ++r) {
            half4 o = { (_Float16)acc[r][0], (_Float16)acc[r][1],
                        (_Float16)acc[r][2], (_Float16)acc[r][3] };
            *(half4*)&outp[(size_t)(row0 + tr + r) * BN + n0 + tnq] = o;
        }
    } else {
#pragma unroll
        for (int i = 0; i < 8; ++i) {
            half4 o = { (_Float16)acc[i][0], (_Float16)acc[i][1],
                        (_Float16)acc[i][2], (_Float16)acc[i][3] };
            *(half4*)&kT[((size_t)b * BN + n0 + tnk + i) * DQ + tdk] = o;
        }
    }
}

// ---------------------------------------------------------------------------
// MFMA flash attention. grid (N/64, B), block 256 (4 waves).
// S: mfma 16x16x32_f16, rows=m cols=n -> per-n stats in-lane + shfl_xor(16,32).
// PV: mfma 32x32x16_f16, rows=c cols=n; wave w owns c in [w*64,(w+1)*64).
// ---------------------------------------------------------------------------
__global__ __launch_bounds__(256, 3) void flash_kernel(
    const _Float16* __restrict__ qb, const _Float16* __restrict__ kT,
    const _Float16* __restrict__ vb, const float* __restrict__ x,
    float* __restrict__ out)
{
    const int t    = threadIdx.x;
    const int lane = t & 63;
    const int w    = t >> 6;
    const int n0   = blockIdx.x * 64;
    const int b    = blockIdx.y;

    __shared__ __align__(16) _Float16 vs[NCH * ROWV];  // [c][m]  36.9 KB
    __shared__ __align__(16) _Float16 Ps[64 * ROWP];   // [n][m]  10.2 KB
    __shared__ float alph_s[64];
    __shared__ float l_s[64];

    const int col   = lane & 15;   // S: n within wave tile
    const int q4    = lane >> 4;   // quad
    const int col32 = lane & 31;   // PV: n within 32-tile
    const int h     = lane >> 5;   // half-wave

    // persistent B_Q frag: B[k=d=q4*8+j][n = n0 + w*16 + col]
    half8 bqf;
    {
        const _Float16* qp = qb + (size_t)b * DQ * BN;
        const int n = n0 + w * 16 + col;
#pragma unroll
        for (int j = 0; j < 8; ++j)
            bqf[j] = qp[(size_t)(q4 * 8 + j) * BN + n];
    }

    floatx16 acc[2][2];   // [ct][nt]
#pragma unroll
    for (int ct = 0; ct < 2; ++ct)
#pragma unroll
        for (int nt = 0; nt < 2; ++nt)
#pragma unroll
            for (int r = 0; r < 16; ++r) acc[ct][nt][r] = 0.0f;

    float m_i = -1e30f, l_i = 0.0f;

    const _Float16* kp = kT + (size_t)b * BN * DQ;
    const _Float16* vp = vb + (size_t)b * NCH * BN;

    for (int mc = 0; mc < BN; mc += 64) {
        // ---- V-chunk global loads (consumed after barrier1) ----
        uint4 stg[8];
#pragma unroll
        for (int i = 0; i < 8; ++i) {
            int idx = i * 256 + t;
            int c = idx >> 3, seg = idx & 7;
            stg[i] = *(const uint4*)&vp[(size_t)c * BN + mc + seg * 8];
        }

        // ---- S = K^T Q : rows m, cols n ----
        floatx4 sf[4];
#pragma unroll
        for (int mt = 0; mt < 4; ++mt) {
            half8 ak = *(const half8*)&kp[(size_t)(mc + mt * 16 + col) * DQ + q4 * 8];
            floatx4 z = { 0.0f, 0.0f, 0.0f, 0.0f };
            sf[mt] = __builtin_amdgcn_mfma_f32_16x16x32_f16(ak, bqf, z, 0, 0, 0);
        }

        // ---- online softmax stats (per n = col, in-lane + cross-quad) ----
        float cmax = -1e30f;
#pragma unroll
        for (int mt = 0; mt < 4; ++mt)
#pragma unroll
            for (int r = 0; r < 4; ++r) cmax = fmaxf(cmax, sf[mt][r]);
        cmax = fmaxf(cmax, __shfl_xor(cmax, 16));
        cmax = fmaxf(cmax, __shfl_xor(cmax, 32));
        float mn = fmaxf(m_i, cmax);
        float al = __expf(m_i - mn);
        float csum = 0.0f;
        half4 pk[4];
#pragma unroll
        for (int mt = 0; mt < 4; ++mt) {
            float p0 = __expf(sf[mt][0] - mn);
            float p1 = __expf(sf[mt][1] - mn);
            float p2 = __expf(sf[mt][2] - mn);
            float p3 = __expf(sf[mt][3] - mn);
            csum += p0 + p1 + p2 + p3;
            pk[mt] = (half4){ (_Float16)p0, (_Float16)p1, (_Float16)p2, (_Float16)p3 };
        }
        csum += __shfl_xor(csum, 16);
        csum += __shfl_xor(csum, 32);
        l_i = l_i * al + csum;
        m_i = mn;

        __syncthreads();   // prev PV done with vs/Ps

        // ---- stage vs, Ps, alpha ----
#pragma unroll
        for (int i = 0; i < 8; ++i) {
            int idx = i * 256 + t;
            int c = idx >> 3, seg = idx & 7;
            *(uint4*)&vs[c * ROWV + seg * 8] = stg[i];
        }
#pragma unroll
        for (int mt = 0; mt < 4; ++mt)
            *(half4*)&Ps[(w * 16 + col) * ROWP + mt * 16 + q4 * 4] = pk[mt];
        if (q4 == 0) alph_s[w * 16 + col] = al;

        __syncthreads();   // vs/Ps/alpha visible

        // ---- rescale O by alpha(n) ----
        float a0 = alph_s[col32];
        float a1 = alph_s[32 + col32];
#pragma unroll
        for (int ct = 0; ct < 2; ++ct)
#pragma unroll
            for (int r = 0; r < 16; ++r) {
                acc[ct][0][r] *= a0;
                acc[ct][1][r] *= a1;
            }

        // ---- O += V P^T : A=V[c][m] from vs, B=P^T[m][n] from Ps ----
#pragma unroll
        for (int ks = 0; ks < 4; ++ks) {
            half8 bp0 = *(const half8*)&Ps[col32 * ROWP + ks * 16 + h * 8];
            half8 bp1 = *(const half8*)&Ps[(32 + col32) * ROWP + ks * 16 + h * 8];
#pragma unroll
            for (int ct = 0; ct < 2; ++ct) {
                half8 av = *(const half8*)&vs[(w * 64 + ct * 32 + col32) * ROWV + ks * 16 + h * 8];
                acc[ct][0] = __builtin_amdgcn_mfma_f32_32x32x16_f16(av, bp0, acc[ct][0], 0, 0, 0);
                acc[ct][1] = __builtin_amdgcn_mfma_f32_32x32x16_f16(av, bp1, acc[ct][1], 0, 0, 0);
            }
        }
    }

    if (q4 == 0) l_s[w * 16 + col] = l_i;
    __syncthreads();
    const float li0 = 1.0f / l_s[col32];
    const float li1 = 1.0f / l_s[32 + col32];

    // ---- epilogue: O/l + x residual; D cols = n -> 128B-contiguous segments ----
    const float* xp = x + (size_t)b * NCH * BN;
    float*       op = out + (size_t)b * NCH * BN;
#pragma unroll
    for (int ct = 0; ct < 2; ++ct)
#pragma unroll
        for (int nt = 0; nt < 2; ++nt) {
            float li = nt ? li1 : li0;
#pragma unroll
            for (int r = 0; r < 16; ++r) {
                int row = (r & 3) + 8 * (r >> 2) + 4 * h;
                int c = w * 64 + ct * 32 + row;
                size_t off = (size_t)c * BN + n0 + nt * 32 + col32;
                op[off] = acc[ct][nt][r] * li + xp[off];
            }
        }
}

extern "C" void kernel_launch(void* const* d_in, const int* in_sizes, int n_in,
                              void* d_out, int out_size, void* d_ws, size_t ws_size,
                              hipStream_t stream)
{
    const float* x  = (const float*)d_in[0];
    const float* Wq = (const float*)d_in[1];
    const float* bq = (const float*)d_in[2];
    const float* Wk = (const float*)d_in[3];
    const float* bk = (const float*)d_in[4];
    const float* Wv = (const float*)d_in[5];
    const float* bv = (const float*)d_in[6];
    float* out = (float*)d_out;

    _Float16* ws = (_Float16*)d_ws;
    _Float16* qb = ws;                               // 8*32*4096   f16 (2 MB)
    _Float16* kT = qb + (size_t)8 * DQ * BN;         // 8*4096*32   f16 (2 MB)
    _Float16* vb = kT + (size_t)8 * BN * DQ;         // 8*256*4096  f16 (16 MB)

    proj_kernel<<<dim3(16, 10, 8), 256, 0, stream>>>(x, Wq, bq, Wk, bk, Wv, bv, qb, kT, vb);
    flash_kernel<<<dim3(BN / 64, 8), 256, 0, stream>>>(qb, kT, vb, x, out);
}

// Round 3
// 320.024 us; speedup vs baseline: 4.7161x; 1.5174x over previous
//
#include <hip/hip_runtime.h>
#include <stdint.h>

#define BN 4096      // N = H*W
#define NCH 256      // C
#define DQ 32        // D = C/8

typedef _Float16 half8  __attribute__((ext_vector_type(8)));
typedef _Float16 half4  __attribute__((ext_vector_type(4)));
typedef float   floatx4  __attribute__((ext_vector_type(4)));
typedef float   floatx16 __attribute__((ext_vector_type(16)));

typedef __attribute__((address_space(1))) const void g1_void;
typedef __attribute__((address_space(3))) void l3_void;

// ---------------------------------------------------------------------------
// Projection -> f16: qb[b][d][n], kT[b][n][d] (transposed), vb[b][c][n]
// grid (16, 10, B): ry=0 -> q, ry=1 -> k (col micro-tile), ry>=2 -> 32 V rows
// (unchanged from R2)
// ---------------------------------------------------------------------------
__global__ __launch_bounds__(256) void proj_kernel(
    const float* __restrict__ x,
    const float* __restrict__ Wq, const float* __restrict__ bq,
    const float* __restrict__ Wk, const float* __restrict__ bk,
    const float* __restrict__ Wv, const float* __restrict__ bv,
    _Float16* __restrict__ qb, _Float16* __restrict__ kT, _Float16* __restrict__ vb)
{
    const int t  = threadIdx.x;
    const int n0 = blockIdx.x * 256;
    const int ry = blockIdx.y;
    const int b  = blockIdx.z;

    __shared__ __align__(16) float xs[32 * 256];   // [cin][n]
    __shared__ float Wt[32 * 33];                  // [cin][row], padded

    const float* Wsrc; const float* bsrc; int row0; const bool isK = (ry == 1);
    if (ry == 0)      { Wsrc = Wq; bsrc = bq; row0 = 0; }
    else if (ry == 1) { Wsrc = Wk; bsrc = bk; row0 = 0; }
    else              { Wsrc = Wv; bsrc = bv; row0 = (ry - 2) * 32; }

    const int tr  = (t >> 6) * 8;
    const int tnq = (t & 63) * 4;
    const int tdk = (t & 7) * 4;
    const int tnk = (t >> 3) * 8;

    float acc[8][4];
    if (!isK) {
#pragma unroll
        for (int r = 0; r < 8; ++r) {
            float bb = bsrc[row0 + tr + r];
#pragma unroll
            for (int j = 0; j < 4; ++j) acc[r][j] = bb;
        }
    } else {
#pragma unroll
        for (int e = 0; e < 4; ++e) {
            float bb = bsrc[tdk + e];
#pragma unroll
            for (int i = 0; i < 8; ++i) acc[i][e] = bb;
        }
    }

    for (int cc = 0; cc < 256; cc += 32) {
        {
            int r  = t >> 3;
            int c4 = (t & 7) * 4;
            float4 wv = *(const float4*)&Wsrc[(row0 + r) * 256 + cc + c4];
            Wt[(c4 + 0) * 33 + r] = wv.x;
            Wt[(c4 + 1) * 33 + r] = wv.y;
            Wt[(c4 + 2) * 33 + r] = wv.z;
            Wt[(c4 + 3) * 33 + r] = wv.w;
        }
#pragma unroll
        for (int i = 0; i < 8; ++i) {
            int idx = t + i * 256;
            int ci  = idx >> 6;
            int n4  = (idx & 63) * 4;
            *(float4*)&xs[ci * 256 + n4] =
                *(const float4*)&x[(b * NCH + cc + ci) * BN + n0 + n4];
        }
        __syncthreads();

        if (!isK) {
#pragma unroll 8
            for (int ci = 0; ci < 32; ++ci) {
                float4 xv = *(const float4*)&xs[ci * 256 + tnq];
#pragma unroll
                for (int r = 0; r < 8; ++r) {
                    float w = Wt[ci * 33 + tr + r];
                    acc[r][0] += w * xv.x;
                    acc[r][1] += w * xv.y;
                    acc[r][2] += w * xv.z;
                    acc[r][3] += w * xv.w;
                }
            }
        } else {
#pragma unroll 8
            for (int ci = 0; ci < 32; ++ci) {
                float4 xa = *(const float4*)&xs[ci * 256 + tnk];
                float4 xb = *(const float4*)&xs[ci * 256 + tnk + 4];
#pragma unroll
                for (int e = 0; e < 4; ++e) {
                    float w = Wt[ci * 33 + tdk + e];
                    acc[0][e] += w * xa.x;
                    acc[1][e] += w * xa.y;
                    acc[2][e] += w * xa.z;
                    acc[3][e] += w * xa.w;
                    acc[4][e] += w * xb.x;
                    acc[5][e] += w * xb.y;
                    acc[6][e] += w * xb.z;
                    acc[7][e] += w * xb.w;
                }
            }
        }
        __syncthreads();
    }

    if (!isK) {
        _Float16* outp = (ry == 0) ? (qb + (size_t)b * DQ * BN)
                                   : (vb + (size_t)b * NCH * BN);
#pragma unroll
        for (int r = 0; r < 8; ++r) {
            half4 o = { (_Float16)acc[r][0], (_Float16)acc[r][1],
                        (_Float16)acc[r][2], (_Float16)acc[r][3] };
            *(half4*)&outp[(size_t)(row0 + tr + r) * BN + n0 + tnq] = o;
        }
    } else {
#pragma unroll
        for (int i = 0; i < 8; ++i) {
            half4 o = { (_Float16)acc[i][0], (_Float16)acc[i][1],
                        (_Float16)acc[i][2], (_Float16)acc[i][3] };
            *(half4*)&kT[((size_t)b * BN + n0 + tnk + i) * DQ + tdk] = o;
        }
    }
}

// ---------------------------------------------------------------------------
// MFMA flash attention, key-split. grid (N/64, 2, B), block 256 (4 waves).
// Each block: 64 queries x 2048 keys (kh half). Emits unnormalized O (f16)
// plus per-row (m, l) for the combine kernel.
// V staged via global_load_lds (XOR-swizzled 128B rows, no VGPR round-trip).
// ---------------------------------------------------------------------------
__global__ __launch_bounds__(256, 3) void flash_kernel(
    const _Float16* __restrict__ qb, const _Float16* __restrict__ kT,
    const _Float16* __restrict__ vb,
    _Float16* __restrict__ Op, float* __restrict__ Ml)
{
    const int t    = threadIdx.x;
    const int lane = t & 63;
    const int w    = t >> 6;
    const int n0   = blockIdx.x * 64;
    const int kh   = blockIdx.y;
    const int b    = blockIdx.z;
    const int kbase = kh * 2048;

    __shared__ __align__(16) _Float16 vs[NCH * 64];  // [c][seg^], 32 KB
    __shared__ __align__(16) _Float16 Ps[64 * 64];   // [n][pair^], 8 KB
    __shared__ float alph_s[64];
    __shared__ float l_s[64];

    const int col   = lane & 15;
    const int q4    = lane >> 4;
    const int col32 = lane & 31;
    const int h     = lane >> 5;

    const _Float16* kp = kT + (size_t)b * BN * DQ;
    const _Float16* vp = vb + (size_t)b * NCH * BN;

    // persistent B_Q frag: B[k=d=q4*8+j][n = n0 + w*16 + col]
    half8 bqf;
    {
        const _Float16* qp = qb + (size_t)b * DQ * BN;
        const int n = n0 + w * 16 + col;
#pragma unroll
        for (int j = 0; j < 8; ++j)
            bqf[j] = qp[(size_t)(q4 * 8 + j) * BN + n];
    }

    floatx16 acc[2][2];
#pragma unroll
    for (int ct = 0; ct < 2; ++ct)
#pragma unroll
        for (int nt = 0; nt < 2; ++nt)
#pragma unroll
            for (int r = 0; r < 16; ++r) acc[ct][nt][r] = 0.0f;

    float m_i = -1e30f, l_i = 0.0f;

    // staging helpers -------------------------------------------------------
    const int sc_loc = lane >> 3;                  // 0..7 row within 8-row call
    const int s_log  = (lane & 7) ^ (sc_loc & 7);  // XOR swizzle
    // K prefetch for iter 0
    half8 ak[4];
#pragma unroll
    for (int mt = 0; mt < 4; ++mt)
        ak[mt] = *(const half8*)&kp[(size_t)(kbase + mt * 16 + col) * DQ + q4 * 8];
    // V stage for iter 0
#pragma unroll
    for (int j = 0; j < 8; ++j) {
        const int c = w * 64 + j * 8 + sc_loc;
        __builtin_amdgcn_global_load_lds(
            (g1_void*)&vp[(size_t)c * BN + kbase + s_log * 8],
            (l3_void*)&vs[(w * 64 + j * 8) * 64], 16, 0, 0);
    }

    for (int it = 0; it < 32; ++it) {
        const int mc = kbase + it * 64;

        // ---- S = K^T Q ----
        floatx4 sf[4];
#pragma unroll
        for (int mt = 0; mt < 4; ++mt) {
            floatx4 z = { 0.0f, 0.0f, 0.0f, 0.0f };
            sf[mt] = __builtin_amdgcn_mfma_f32_16x16x32_f16(ak[mt], bqf, z, 0, 0, 0);
        }

        // ---- online softmax stats ----
        float cmax = -1e30f;
#pragma unroll
        for (int mt = 0; mt < 4; ++mt)
#pragma unroll
            for (int r = 0; r < 4; ++r) cmax = fmaxf(cmax, sf[mt][r]);
        cmax = fmaxf(cmax, __shfl_xor(cmax, 16));
        cmax = fmaxf(cmax, __shfl_xor(cmax, 32));
        float mn = fmaxf(m_i, cmax);
        float al = __expf(m_i - mn);
        float csum = 0.0f;
        half4 pk[4];
#pragma unroll
        for (int mt = 0; mt < 4; ++mt) {
            float p0 = __expf(sf[mt][0] - mn);
            float p1 = __expf(sf[mt][1] - mn);
            float p2 = __expf(sf[mt][2] - mn);
            float p3 = __expf(sf[mt][3] - mn);
            csum += p0 + p1 + p2 + p3;
            pk[mt] = (half4){ (_Float16)p0, (_Float16)p1, (_Float16)p2, (_Float16)p3 };
        }
        csum += __shfl_xor(csum, 16);
        csum += __shfl_xor(csum, 32);
        l_i = l_i * al + csum;
        m_i = mn;

        // ---- write Ps (XOR-swizzled pairs), alpha ----
        {
            const int n = w * 16 + col;
#pragma unroll
            for (int mt = 0; mt < 4; ++mt) {
                const int p_log = 2 * mt + (q4 >> 1);
                const int p_phys = p_log ^ (n & 7);
                *(half4*)((char*)&Ps[n * 64] + p_phys * 16 + (q4 & 1) * 8) = pk[mt];
            }
            if (q4 == 0) alph_s[n] = al;
        }

        __syncthreads();   // Ps visible; vs(it) load-queue drained

        // ---- rescale O ----
        float a0 = alph_s[col32];
        float a1 = alph_s[32 + col32];
#pragma unroll
        for (int ct = 0; ct < 2; ++ct)
#pragma unroll
            for (int r = 0; r < 16; ++r) {
                acc[ct][0][r] *= a0;
                acc[ct][1][r] *= a1;
            }

        // ---- O += V P^T ----
#pragma unroll
        for (int ks = 0; ks < 4; ++ks) {
            const int p_log = 2 * ks + h;
            half8 bp0 = *(const half8*)((char*)&Ps[col32 * 64] + (p_log ^ (col32 & 7)) * 16);
            half8 bp1 = *(const half8*)((char*)&Ps[(32 + col32) * 64] + (p_log ^ (col32 & 7)) * 16);
#pragma unroll
            for (int ct = 0; ct < 2; ++ct) {
                const int c = w * 64 + ct * 32 + col32;
                half8 av = *(const half8*)((char*)&vs[c * 64] + ((p_log ^ (c & 7)) * 16));
                acc[ct][0] = __builtin_amdgcn_mfma_f32_32x32x16_f16(av, bp0, acc[ct][0], 0, 0, 0);
                acc[ct][1] = __builtin_amdgcn_mfma_f32_32x32x16_f16(av, bp1, acc[ct][1], 0, 0, 0);
            }
        }

        __syncthreads();   // all waves done reading vs/Ps

        // ---- prefetch next: K regs first, then async V->LDS ----
        if (it < 31) {
            const int mcn = mc + 64;
#pragma unroll
            for (int mt = 0; mt < 4; ++mt)
                ak[mt] = *(const half8*)&kp[(size_t)(mcn + mt * 16 + col) * DQ + q4 * 8];
#pragma unroll
            for (int j = 0; j < 8; ++j) {
                const int c = w * 64 + j * 8 + sc_loc;
                __builtin_amdgcn_global_load_lds(
                    (g1_void*)&vp[(size_t)c * BN + mcn + s_log * 8],
                    (l3_void*)&vs[(w * 64 + j * 8) * 64], 16, 0, 0);
            }
        }
    }

    // ---- epilogue: unnormalized O (f16) + (m,l) ----
    if (q4 == 0) {
        const int n = n0 + w * 16 + col;
        Ml[(size_t)(kh * 8 + b) * BN + n] = m_i;
        Ml[(size_t)(16 + kh * 8 + b) * BN + n] = l_i;
    }
    _Float16* Opp = Op + (size_t)(kh * 8 + b) * NCH * BN;
#pragma unroll
    for (int ct = 0; ct < 2; ++ct)
#pragma unroll
        for (int nt = 0; nt < 2; ++nt)
#pragma unroll
            for (int r = 0; r < 16; ++r) {
                int row = (r & 3) + 8 * (r >> 2) + 4 * h;
                int c = w * 64 + ct * 32 + row;
                Opp[(size_t)c * BN + n0 + nt * 32 + col32] = (_Float16)acc[ct][nt][r];
            }
}

// ---------------------------------------------------------------------------
// Combine: out = (O0*e^{m0-M} + O1*e^{m1-M}) / (l0*e^{m0-M} + l1*e^{m1-M}) + x
// grid (16, 16, 8), block 256: thread = one n, 16 channels.
// ---------------------------------------------------------------------------
__global__ __launch_bounds__(256) void combine_kernel(
    const _Float16* __restrict__ Op, const float* __restrict__ Ml,
    const float* __restrict__ x, float* __restrict__ out)
{
    const int n = blockIdx.x * 256 + threadIdx.x;
    const int c0 = blockIdx.y * 16;
    const int b = blockIdx.z;

    const float m0 = Ml[(size_t)b * BN + n];
    const float m1 = Ml[(size_t)(8 + b) * BN + n];
    const float l0 = Ml[(size_t)(16 + b) * BN + n];
    const float l1 = Ml[(size_t)(24 + b) * BN + n];
    const float M = fmaxf(m0, m1);
    const float a0 = __expf(m0 - M);
    const float a1 = __expf(m1 - M);
    const float inv = 1.0f / (l0 * a0 + l1 * a1);
    const float f0 = a0 * inv;
    const float f1 = a1 * inv;

    const _Float16* Op0 = Op + (size_t)b * NCH * BN;
    const _Float16* Op1 = Op + (size_t)(8 + b) * NCH * BN;
#pragma unroll 4
    for (int ci = 0; ci < 16; ++ci) {
        const int c = c0 + ci;
        const size_t off = ((size_t)b * NCH + c) * BN + n;
        const size_t po = (size_t)c * BN + n;
        out[off] = (float)Op0[po] * f0 + (float)Op1[po] * f1 + x[off];
    }
}

extern "C" void kernel_launch(void* const* d_in, const int* in_sizes, int n_in,
                              void* d_out, int out_size, void* d_ws, size_t ws_size,
                              hipStream_t stream)
{
    const float* x  = (const float*)d_in[0];
    const float* Wq = (const float*)d_in[1];
    const float* bq = (const float*)d_in[2];
    const float* Wk = (const float*)d_in[3];
    const float* bk = (const float*)d_in[4];
    const float* Wv = (const float*)d_in[5];
    const float* bv = (const float*)d_in[6];
    float* out = (float*)d_out;

    _Float16* ws = (_Float16*)d_ws;
    _Float16* qb = ws;                               // 8*32*4096   f16 (2 MB)
    _Float16* kT = qb + (size_t)8 * DQ * BN;         // 8*4096*32   f16 (2 MB)
    _Float16* vb = kT + (size_t)8 * BN * DQ;         // 8*256*4096  f16 (16 MB)
    _Float16* Op = vb + (size_t)8 * NCH * BN;        // 2*8*256*4096 f16 (32 MB)
    float*    Ml = (float*)(Op + (size_t)2 * 8 * NCH * BN);  // 4*8*4096 f32 (0.5 MB)

    proj_kernel<<<dim3(16, 10, 8), 256, 0, stream>>>(x, Wq, bq, Wk, bk, Wv, bv, qb, kT, vb);
    flash_kernel<<<dim3(BN / 64, 2, 8), 256, 0, stream>>>(qb, kT, vb, Op, Ml);
    combine_kernel<<<dim3(16, 16, 8), 256, 0, stream>>>(Op, Ml, x, out);
}

// Round 4
// 254.750 us; speedup vs baseline: 5.9245x; 1.2562x over previous
//
#include <hip/hip_runtime.h>
#include <stdint.h>

#define BN 4096      // N = H*W
#define NCH 256      // C
#define DQ 32        // D = C/8

typedef _Float16 half8  __attribute__((ext_vector_type(8)));
typedef _Float16 half4  __attribute__((ext_vector_type(4)));
typedef float   floatx4  __attribute__((ext_vector_type(4)));
typedef float   floatx16 __attribute__((ext_vector_type(16)));

typedef __attribute__((address_space(1))) const void g1_void;
typedef __attribute__((address_space(3))) void l3_void;

// ---------------------------------------------------------------------------
// convert_w: cast Wq|Wk|Wv (fp32) into one concatenated f16 buffer.
// layout: [0..8191]=Wq, [8192..16383]=Wk, [16384..81919]=Wv. grid 80 x 256.
// ---------------------------------------------------------------------------
__global__ __launch_bounds__(256) void convert_w(
    const float* __restrict__ Wq, const float* __restrict__ Wk,
    const float* __restrict__ Wv, _Float16* __restrict__ W16)
{
    int e4 = (blockIdx.x * 256 + threadIdx.x) * 4;
    float4 v;
    if (e4 < 8192)        v = *(const float4*)&Wq[e4];
    else if (e4 < 16384)  v = *(const float4*)&Wk[e4 - 8192];
    else                  v = *(const float4*)&Wv[e4 - 16384];
    half4 h = { (_Float16)v.x, (_Float16)v.y, (_Float16)v.z, (_Float16)v.w };
    *(half4*)&W16[e4] = h;
}

// ---------------------------------------------------------------------------
// MFMA projection. grid (32, 8) = (n-tile of 128, batch); block 512 (8 waves).
// LDS: xT[n 128][k 256] f16 (64 KB), 16B segments XOR-swizzled by (n>>2)&31.
// q/k: D[n][d] = xT * Wq^T  (A = x-frag, B = W-frag from global f16)
// v  : D[c][n] = Wv * xT    (A = W-frag, B = x-frag) -> vb[c][n]
// waves: nc = w&3 (32-n chunk); job = w>>2: 0 -> q,k,v rg0-2; 1 -> v rg3-7.
// ---------------------------------------------------------------------------
__global__ __launch_bounds__(512) void proj_kernel(
    const float* __restrict__ x, const _Float16* __restrict__ W16,
    const float* __restrict__ bq, const float* __restrict__ bk,
    const float* __restrict__ bv,
    _Float16* __restrict__ qT, _Float16* __restrict__ kT,
    _Float16* __restrict__ vb)
{
    const int t  = threadIdx.x;
    const int n0 = blockIdx.x * 128;
    const int b  = blockIdx.y;

    __shared__ __align__(16) _Float16 xTl[128 * 256];  // 64 KB

    // ---- stage x^T (fp32 -> f16, transposed, swizzled) ----
#pragma unroll
    for (int p = 0; p < 2; ++p) {
        const int kb = p * 128 + (t >> 5) * 8;
        const int n4 = (t & 31) * 4;
        float4 xr[8];
#pragma unroll
        for (int i = 0; i < 8; ++i)
            xr[i] = *(const float4*)&x[((size_t)b * NCH + kb + i) * BN + n0 + n4];
        const float* xf = (const float*)xr;
#pragma unroll
        for (int j = 0; j < 4; ++j) {
            const int n = n4 + j;
            half8 hv;
#pragma unroll
            for (int i = 0; i < 8; ++i) hv[i] = (_Float16)xf[i * 4 + j];
            const int phys = (kb >> 3) ^ ((n >> 2) & 31);
            *(half8*)&xTl[n * 256 + phys * 8] = hv;
        }
    }
    __syncthreads();

    const int lane  = t & 63;
    const int w     = t >> 6;
    const int col32 = lane & 31;
    const int h     = lane >> 5;
    const int nc    = w & 3;
    const int job   = w >> 2;

    const _Float16* Wq16 = W16;
    const _Float16* Wk16 = W16 + 8192;
    const _Float16* Wv16 = W16 + 16384;

    // x-frag: A or B operand, lane index = n = nc*32+col32, k = ks*16 + h*8 + j
#define XFRAG(ks) (*(const half8*)&xTl[(nc * 32 + col32) * 256 + \
        (((ks) * 2 + h) ^ (((nc * 32 + col32) >> 2) & 31)) * 8])

    if (job == 0) {
        // ---- q and k: D[n][d] ----
        const float bqv = bq[col32];
        const float bkv = bk[col32];
        floatx16 aq, ak2;
#pragma unroll
        for (int r = 0; r < 16; ++r) { aq[r] = 0.0f; ak2[r] = 0.0f; }
#pragma unroll
        for (int ks = 0; ks < 16; ++ks) {
            half8 xa = XFRAG(ks);
            half8 wqf = *(const half8*)&Wq16[col32 * 256 + ks * 16 + h * 8];
            half8 wkf = *(const half8*)&Wk16[col32 * 256 + ks * 16 + h * 8];
            aq  = __builtin_amdgcn_mfma_f32_32x32x16_f16(xa, wqf, aq, 0, 0, 0);
            ak2 = __builtin_amdgcn_mfma_f32_32x32x16_f16(xa, wkf, ak2, 0, 0, 0);
        }
#pragma unroll
        for (int r = 0; r < 16; ++r) {
            const int n = n0 + nc * 32 + (r & 3) + 8 * (r >> 2) + 4 * h;
            qT[((size_t)b * BN + n) * DQ + col32] = (_Float16)(aq[r] + bqv);
            kT[((size_t)b * BN + n) * DQ + col32] = (_Float16)(ak2[r] + bkv);
        }
    }

    // ---- v row-groups: D[c][n] ----
    const int rg_lo = (job == 0) ? 0 : 3;
    const int rg_hi = (job == 0) ? 3 : 8;
    for (int rg = rg_lo; rg < rg_hi; ++rg) {
        floatx16 av;
#pragma unroll
        for (int r = 0; r < 16; ++r) av[r] = 0.0f;
#pragma unroll
        for (int ks = 0; ks < 16; ++ks) {
            half8 xb  = XFRAG(ks);
            half8 wvf = *(const half8*)&Wv16[(rg * 32 + col32) * 256 + ks * 16 + h * 8];
            av = __builtin_amdgcn_mfma_f32_32x32x16_f16(wvf, xb, av, 0, 0, 0);
        }
#pragma unroll
        for (int r = 0; r < 16; ++r) {
            const int c = rg * 32 + (r & 3) + 8 * (r >> 2) + 4 * h;
            vb[((size_t)b * NCH + c) * BN + n0 + nc * 32 + col32] =
                (_Float16)(av[r] + bv[c]);
        }
    }
#undef XFRAG
}

// ---------------------------------------------------------------------------
// MFMA flash attention, key-split. grid (N/64, 2, B), block 256 (4 waves).
// (unchanged from R3 except q read: one b128 from qT[n][d])
// ---------------------------------------------------------------------------
__global__ __launch_bounds__(256, 3) void flash_kernel(
    const _Float16* __restrict__ qT, const _Float16* __restrict__ kT,
    const _Float16* __restrict__ vb,
    _Float16* __restrict__ Op, float* __restrict__ Ml)
{
    const int t    = threadIdx.x;
    const int lane = t & 63;
    const int w    = t >> 6;
    const int n0   = blockIdx.x * 64;
    const int kh   = blockIdx.y;
    const int b    = blockIdx.z;
    const int kbase = kh * 2048;

    __shared__ __align__(16) _Float16 vs[NCH * 64];  // [c][seg^], 32 KB
    __shared__ __align__(16) _Float16 Ps[64 * 64];   // [n][pair^], 8 KB
    __shared__ float alph_s[64];
    __shared__ float l_s[64];

    const int col   = lane & 15;
    const int q4    = lane >> 4;
    const int col32 = lane & 31;
    const int h     = lane >> 5;

    const _Float16* kp = kT + (size_t)b * BN * DQ;
    const _Float16* vp = vb + (size_t)b * NCH * BN;

    // persistent B_Q frag: B[k=d=q4*8+j][n = n0 + w*16 + col]
    half8 bqf = *(const half8*)&qT[((size_t)b * BN + n0 + w * 16 + col) * DQ + q4 * 8];

    floatx16 acc[2][2];
#pragma unroll
    for (int ct = 0; ct < 2; ++ct)
#pragma unroll
        for (int nt = 0; nt < 2; ++nt)
#pragma unroll
            for (int r = 0; r < 16; ++r) acc[ct][nt][r] = 0.0f;

    float m_i = -1e30f, l_i = 0.0f;

    const int sc_loc = lane >> 3;
    const int s_log  = (lane & 7) ^ (sc_loc & 7);
    half8 ak[4];
#pragma unroll
    for (int mt = 0; mt < 4; ++mt)
        ak[mt] = *(const half8*)&kp[(size_t)(kbase + mt * 16 + col) * DQ + q4 * 8];
#pragma unroll
    for (int j = 0; j < 8; ++j) {
        const int c = w * 64 + j * 8 + sc_loc;
        __builtin_amdgcn_global_load_lds(
            (g1_void*)&vp[(size_t)c * BN + kbase + s_log * 8],
            (l3_void*)&vs[(w * 64 + j * 8) * 64], 16, 0, 0);
    }

    for (int it = 0; it < 32; ++it) {
        const int mc = kbase + it * 64;

        floatx4 sf[4];
#pragma unroll
        for (int mt = 0; mt < 4; ++mt) {
            floatx4 z = { 0.0f, 0.0f, 0.0f, 0.0f };
            sf[mt] = __builtin_amdgcn_mfma_f32_16x16x32_f16(ak[mt], bqf, z, 0, 0, 0);
        }

        float cmax = -1e30f;
#pragma unroll
        for (int mt = 0; mt < 4; ++mt)
#pragma unroll
            for (int r = 0; r < 4; ++r) cmax = fmaxf(cmax, sf[mt][r]);
        cmax = fmaxf(cmax, __shfl_xor(cmax, 16));
        cmax = fmaxf(cmax, __shfl_xor(cmax, 32));
        float mn = fmaxf(m_i, cmax);
        float al = __expf(m_i - mn);
        float csum = 0.0f;
        half4 pk[4];
#pragma unroll
        for (int mt = 0; mt < 4; ++mt) {
            float p0 = __expf(sf[mt][0] - mn);
            float p1 = __expf(sf[mt][1] - mn);
            float p2 = __expf(sf[mt][2] - mn);
            float p3 = __expf(sf[mt][3] - mn);
            csum += p0 + p1 + p2 + p3;
            pk[mt] = (half4){ (_Float16)p0, (_Float16)p1, (_Float16)p2, (_Float16)p3 };
        }
        csum += __shfl_xor(csum, 16);
        csum += __shfl_xor(csum, 32);
        l_i = l_i * al + csum;
        m_i = mn;

        {
            const int n = w * 16 + col;
#pragma unroll
            for (int mt = 0; mt < 4; ++mt) {
                const int p_log = 2 * mt + (q4 >> 1);
                const int p_phys = p_log ^ (n & 7);
                *(half4*)((char*)&Ps[n * 64] + p_phys * 16 + (q4 & 1) * 8) = pk[mt];
            }
            if (q4 == 0) alph_s[n] = al;
        }

        __syncthreads();

        float a0 = alph_s[col32];
        float a1 = alph_s[32 + col32];
#pragma unroll
        for (int ct = 0; ct < 2; ++ct)
#pragma unroll
            for (int r = 0; r < 16; ++r) {
                acc[ct][0][r] *= a0;
                acc[ct][1][r] *= a1;
            }

#pragma unroll
        for (int ks = 0; ks < 4; ++ks) {
            const int p_log = 2 * ks + h;
            half8 bp0 = *(const half8*)((char*)&Ps[col32 * 64] + (p_log ^ (col32 & 7)) * 16);
            half8 bp1 = *(const half8*)((char*)&Ps[(32 + col32) * 64] + (p_log ^ (col32 & 7)) * 16);
#pragma unroll
            for (int ct = 0; ct < 2; ++ct) {
                const int c = w * 64 + ct * 32 + col32;
                half8 av = *(const half8*)((char*)&vs[c * 64] + ((p_log ^ (c & 7)) * 16));
                acc[ct][0] = __builtin_amdgcn_mfma_f32_32x32x16_f16(av, bp0, acc[ct][0], 0, 0, 0);
                acc[ct][1] = __builtin_amdgcn_mfma_f32_32x32x16_f16(av, bp1, acc[ct][1], 0, 0, 0);
            }
        }

        __syncthreads();

        if (it < 31) {
            const int mcn = mc + 64;
#pragma unroll
            for (int mt = 0; mt < 4; ++mt)
                ak[mt] = *(const half8*)&kp[(size_t)(mcn + mt * 16 + col) * DQ + q4 * 8];
#pragma unroll
            for (int j = 0; j < 8; ++j) {
                const int c = w * 64 + j * 8 + sc_loc;
                __builtin_amdgcn_global_load_lds(
                    (g1_void*)&vp[(size_t)c * BN + mcn + s_log * 8],
                    (l3_void*)&vs[(w * 64 + j * 8) * 64], 16, 0, 0);
            }
        }
    }

    if (q4 == 0) {
        const int n = n0 + w * 16 + col;
        Ml[(size_t)(kh * 8 + b) * BN + n] = m_i;
        Ml[(size_t)(16 + kh * 8 + b) * BN + n] = l_i;
    }
    _Float16* Opp = Op + (size_t)(kh * 8 + b) * NCH * BN;
#pragma unroll
    for (int ct = 0; ct < 2; ++ct)
#pragma unroll
        for (int nt = 0; nt < 2; ++nt)
#pragma unroll
            for (int r = 0; r < 16; ++r) {
                int row = (r & 3) + 8 * (r >> 2) + 4 * h;
                int c = w * 64 + ct * 32 + row;
                Opp[(size_t)c * BN + n0 + nt * 32 + col32] = (_Float16)acc[ct][nt][r];
            }
}

// ---------------------------------------------------------------------------
// Combine (unchanged from R3)
// ---------------------------------------------------------------------------
__global__ __launch_bounds__(256) void combine_kernel(
    const _Float16* __restrict__ Op, const float* __restrict__ Ml,
    const float* __restrict__ x, float* __restrict__ out)
{
    const int n = blockIdx.x * 256 + threadIdx.x;
    const int c0 = blockIdx.y * 16;
    const int b = blockIdx.z;

    const float m0 = Ml[(size_t)b * BN + n];
    const float m1 = Ml[(size_t)(8 + b) * BN + n];
    const float l0 = Ml[(size_t)(16 + b) * BN + n];
    const float l1 = Ml[(size_t)(24 + b) * BN + n];
    const float M = fmaxf(m0, m1);
    const float a0 = __expf(m0 - M);
    const float a1 = __expf(m1 - M);
    const float inv = 1.0f / (l0 * a0 + l1 * a1);
    const float f0 = a0 * inv;
    const float f1 = a1 * inv;

    const _Float16* Op0 = Op + (size_t)b * NCH * BN;
    const _Float16* Op1 = Op + (size_t)(8 + b) * NCH * BN;
#pragma unroll 4
    for (int ci = 0; ci < 16; ++ci) {
        const int c = c0 + ci;
        const size_t off = ((size_t)b * NCH + c) * BN + n;
        const size_t po = (size_t)c * BN + n;
        out[off] = (float)Op0[po] * f0 + (float)Op1[po] * f1 + x[off];
    }
}

extern "C" void kernel_launch(void* const* d_in, const int* in_sizes, int n_in,
                              void* d_out, int out_size, void* d_ws, size_t ws_size,
                              hipStream_t stream)
{
    const float* x  = (const float*)d_in[0];
    const float* Wq = (const float*)d_in[1];
    const float* bq = (const float*)d_in[2];
    const float* Wk = (const float*)d_in[3];
    const float* bk = (const float*)d_in[4];
    const float* Wv = (const float*)d_in[5];
    const float* bv = (const float*)d_in[6];
    float* out = (float*)d_out;

    _Float16* ws = (_Float16*)d_ws;
    _Float16* W16 = ws;                               // 81920 f16 (160 KB)
    _Float16* qT  = W16 + 81920;                      // 8*4096*32 f16 (2 MB)
    _Float16* kT  = qT + (size_t)8 * BN * DQ;         // 8*4096*32 f16 (2 MB)
    _Float16* vb  = kT + (size_t)8 * BN * DQ;         // 8*256*4096 f16 (16 MB)
    _Float16* Op  = vb + (size_t)8 * NCH * BN;        // 2*8*256*4096 f16 (32 MB)
    float*    Ml  = (float*)(Op + (size_t)2 * 8 * NCH * BN);  // 0.5 MB

    convert_w<<<dim3(80), 256, 0, stream>>>(Wq, Wk, Wv, W16);
    proj_kernel<<<dim3(32, 8), 512, 0, stream>>>(x, W16, bq, bk, bv, qT, kT, vb);
    flash_kernel<<<dim3(BN / 64, 2, 8), 256, 0, stream>>>(qT, kT, vb, Op, Ml);
    combine_kernel<<<dim3(16, 16, 8), 256, 0, stream>>>(Op, Ml, x, out);
}